// Round 1
// baseline (79.404 us; speedup 1.0000x reference)
//
#include <hip/hip_runtime.h>

#define BHW      (8 * 128 * 128)        // 131072 pixels
#define HW       (128 * 128)            // 16384
#define NCLASS   121

// d_out layout (flat f32, return order: pred, m_mask, disappear, appear)
#define OFF_PRED 0
#define OFF_MASK (8 * 3 * HW)                    // 393216
#define OFF_DIS  (OFF_MASK + 8 * NCLASS * HW)    // 16252928
#define OFF_APP  (OFF_DIS + 8 * HW)              // 16384000

// Kernel A: decode motion, write dense m_mask (121 ch/pixel), scatter 4 bilinear
// weights into seg (workspace) at the shifted target pixels.
__global__ void kernel_mask_seg(const float* __restrict__ motion,
                                float* __restrict__ out,
                                float* __restrict__ seg) {
    int p = blockIdx.x * blockDim.x + threadIdx.x;
    if (p >= BHW) return;
    int b   = p >> 14;
    int pix = p & (HW - 1);
    int y   = pix >> 7;
    int x   = pix & 127;

    float mx = motion[(size_t)(b * 2 + 0) * HW + pix];
    float my = motion[(size_t)(b * 2 + 1) * HW + pix];
    float flx = floorf(mx), fly = floorf(my);
    float fa = mx - flx;            // frac for x (a / ka axis)
    float fb = my - fly;            // frac for y (b / kb axis)
    int ia = (int)flx + 5;          // in [0, 9]
    int ib = (int)fly + 5;          // in [0, 9]

    // dense m_mask write: channel c = kb*11 + ka, value bvec[kb]*avec[ka]
    float* mm = out + OFF_MASK + (size_t)b * NCLASS * HW + pix;
    #pragma unroll
    for (int kb = 0; kb < 11; ++kb) {
        float bv = (kb == ib) ? (1.0f - fb) : (kb == ib + 1) ? fb : 0.0f;
        #pragma unroll
        for (int ka = 0; ka < 11; ++ka) {
            float av = (ka == ia) ? (1.0f - fa) : (ka == ia + 1) ? fa : 0.0f;
            mm[(size_t)(kb * 11 + ka) * HW] = bv * av;
        }
    }

    // seg scatter: channel (kb,ka) at source (y,x) contributes to target
    // t = (y - kb + 5, x - ka + 5)
    float wa0 = 1.0f - fa, wa1 = fa;
    float wb0 = 1.0f - fb, wb1 = fb;
    float* segb = seg + (size_t)b * HW;
    #pragma unroll
    for (int j = 0; j < 2; ++j) {       // kb = ib + j
        int ty = y - (ib + j) + 5;
        if (ty < 0 || ty >= 128) continue;
        float wb = j ? wb1 : wb0;
        #pragma unroll
        for (int i = 0; i < 2; ++i) {   // ka = ia + i
            int tx = x - (ia + i) + 5;
            if (tx < 0 || tx >= 128) continue;
            float w = wb * (i ? wa1 : wa0);
            atomicAdd(&segb[ty * 128 + tx], w);
        }
    }
}

// Kernel B: per pixel: disappear/appear from seg (dense writes), compute
// im = im_input[:,3:]*(1-disappear) locally, scatter w*im into pred (12 atomics).
__global__ void kernel_seg_pred(const float* __restrict__ motion,
                                const float* __restrict__ im_input,
                                const float* __restrict__ seg,
                                float* __restrict__ out) {
    int p = blockIdx.x * blockDim.x + threadIdx.x;
    if (p >= BHW) return;
    int b   = p >> 14;
    int pix = p & (HW - 1);
    int y   = pix >> 7;
    int x   = pix & 127;

    float s   = seg[p];
    float dis = fmaxf(s - 1.0f, 0.0f);
    float app = fmaxf(1.0f - s, 0.0f);
    out[OFF_DIS + (size_t)p] = dis;
    out[OFF_APP + (size_t)p] = app;

    float scale = 1.0f - dis;
    const float* imb = im_input + (size_t)b * 6 * HW + pix;
    float im0 = imb[(size_t)3 * HW] * scale;
    float im1 = imb[(size_t)4 * HW] * scale;
    float im2 = imb[(size_t)5 * HW] * scale;

    float mx = motion[(size_t)(b * 2 + 0) * HW + pix];
    float my = motion[(size_t)(b * 2 + 1) * HW + pix];
    float flx = floorf(mx), fly = floorf(my);
    float fa = mx - flx;
    float fb = my - fly;
    int ia = (int)flx + 5;
    int ib = (int)fly + 5;
    float wa0 = 1.0f - fa, wa1 = fa;
    float wb0 = 1.0f - fb, wb1 = fb;

    float* predb = out + OFF_PRED + (size_t)b * 3 * HW;
    #pragma unroll
    for (int j = 0; j < 2; ++j) {
        int ty = y - (ib + j) + 5;
        if (ty < 0 || ty >= 128) continue;
        float wb = j ? wb1 : wb0;
        #pragma unroll
        for (int i = 0; i < 2; ++i) {
            int tx = x - (ia + i) + 5;
            if (tx < 0 || tx >= 128) continue;
            float w = wb * (i ? wa1 : wa0);
            int t = ty * 128 + tx;
            atomicAdd(&predb[t],           w * im0);
            atomicAdd(&predb[HW + t],      w * im1);
            atomicAdd(&predb[2 * HW + t],  w * im2);
        }
    }
}

extern "C" void kernel_launch(void* const* d_in, const int* in_sizes, int n_in,
                              void* d_out, int out_size, void* d_ws, size_t ws_size,
                              hipStream_t stream) {
    const float* im_input = (const float*)d_in[0];   // (8, 6, 128, 128)
    const float* motion   = (const float*)d_in[1];   // (8, 2, 128, 128)
    // d_in[2] = m_kernel: identity by construction, unused.

    float* out = (float*)d_out;
    float* seg = (float*)d_ws;                       // B*H*W f32 = 512 KB

    // zero the scatter destinations (atomics accumulate; must reset every call)
    hipMemsetAsync(out, 0, (size_t)OFF_MASK * sizeof(float), stream);   // pred
    hipMemsetAsync(seg, 0, (size_t)BHW * sizeof(float), stream);

    dim3 block(256);
    dim3 grid((BHW + 255) / 256);
    kernel_mask_seg<<<grid, block, 0, stream>>>(motion, out, seg);
    kernel_seg_pred<<<grid, block, 0, stream>>>(motion, im_input, seg, out);
}

// Round 2
// 35.688 us; speedup vs baseline: 2.2249x; 2.2249x over previous
//
#include <hip/hip_runtime.h>

#define HW       16384                  // 128*128
#define NCLASS   121

// d_out layout (flat f32, return order: pred, m_mask, disappear, appear)
#define OFF_PRED 0
#define OFF_MASK (8 * 3 * HW)                    // 393216
#define OFF_DIS  (OFF_MASK + 8 * NCLASS * HW)    // 16252928
#define OFF_APP  (OFF_DIS + 8 * HW)              // 16384000

#define TBX  32
#define TBY  8
#define HALO 5
#define LX   (TBX + 2 * HALO)   // 42
#define LY   (TBY + 2 * HALO)   // 18

// hat(u) = max(0, 1-|u|): exact bilinear one-hot weight for integer offset u.

// Kernel 1: per 32x8 tile — stage motion (+halo, sentinel) in LDS; write dense
// m_mask (121 ch), gather seg from 11x11 window, write disappear/appear.
__global__ __launch_bounds__(256) void k_mask_seg(const float* __restrict__ motion,
                                                  float* __restrict__ out) {
    __shared__ float2 smot[LY][LX];
    int blk = blockIdx.x;
    int b   = blk >> 6;                  // 64 tiles per image (4 x 16)
    int t   = blk & 63;
    int by0 = (t >> 2) * TBY;
    int bx0 = (t & 3) * TBX;
    int tid = threadIdx.x;

    const float* motx = motion + (size_t)(b * 2) * HW;
    const float* moty = motx + HW;
    for (int i = tid; i < LX * LY; i += 256) {
        int ly = i / LX, lx = i - ly * LX;
        int gy = by0 + ly - HALO, gx = bx0 + lx - HALO;
        float2 m;
        if (gy >= 0 && gy < 128 && gx >= 0 && gx < 128) {
            int g = gy * 128 + gx;
            m.x = motx[g];
            m.y = moty[g];
        } else {
            m.x = 1e9f;
            m.y = 1e9f;
        }
        smot[ly][lx] = m;
    }
    __syncthreads();

    int lx = tid & 31, ly = tid >> 5;    // 32 x 8 targets
    int y = by0 + ly, x = bx0 + lx;
    float2 mc = smot[ly + HALO][lx + HALO];

    float av[11], bv[11];
    #pragma unroll
    for (int k = 0; k < 11; ++k) {
        av[k] = fmaxf(0.f, 1.f - fabsf(mc.x - (float)(k - 5)));
        bv[k] = fmaxf(0.f, 1.f - fabsf(mc.y - (float)(k - 5)));
    }

    // dense m_mask write: channel c = kb*11 + ka, value bv[kb]*av[ka]
    float* mm = out + OFF_MASK + (size_t)b * NCLASS * HW + y * 128 + x;
    #pragma unroll
    for (int kb = 0; kb < 11; ++kb) {
        #pragma unroll
        for (int ka = 0; ka < 11; ++ka) {
            mm[(size_t)(kb * 11 + ka) * HW] = bv[kb] * av[ka];
        }
    }

    // seg gather: seg(t) = sum over sources s=t+(dy,dx) of hat products
    float seg = 0.f;
    #pragma unroll
    for (int dy = -5; dy <= 5; ++dy) {
        #pragma unroll
        for (int dx = -5; dx <= 5; ++dx) {
            float2 m = smot[ly + HALO + dy][lx + HALO + dx];
            float wb = 1.f - fabsf(m.y - (float)dy);
            float wa = 1.f - fabsf(m.x - (float)dx);
            if (wb > 0.f && wa > 0.f) seg += wb * wa;
        }
    }

    int p = b * HW + y * 128 + x;
    out[OFF_DIS + p] = fmaxf(seg - 1.f, 0.f);
    out[OFF_APP + p] = fmaxf(1.f - seg, 0.f);
}

// Kernel 2: per 32x8 tile — stage motion + (1-dis)-scaled im (float4) in LDS;
// gather pred(t) = sum w(s,t) * im_scaled(s) over the 11x11 window.
__global__ __launch_bounds__(256) void k_pred(const float* __restrict__ motion,
                                               const float* __restrict__ im_input,
                                               float* __restrict__ out) {
    __shared__ float2 smot[LY][LX];
    __shared__ float4 sim[LY][LX];
    int blk = blockIdx.x;
    int b   = blk >> 6;
    int t   = blk & 63;
    int by0 = (t >> 2) * TBY;
    int bx0 = (t & 3) * TBX;
    int tid = threadIdx.x;

    const float* motx = motion + (size_t)(b * 2) * HW;
    const float* moty = motx + HW;
    const float* imb  = im_input + (size_t)b * 6 * HW;
    const float* disb = out + OFF_DIS + (size_t)b * HW;
    for (int i = tid; i < LX * LY; i += 256) {
        int ly = i / LX, lx = i - ly * LX;
        int gy = by0 + ly - HALO, gx = bx0 + lx - HALO;
        float2 m;
        float4 v;
        if (gy >= 0 && gy < 128 && gx >= 0 && gx < 128) {
            int g = gy * 128 + gx;
            m.x = motx[g];
            m.y = moty[g];
            float sc = 1.f - disb[g];
            v.x = imb[(size_t)3 * HW + g] * sc;
            v.y = imb[(size_t)4 * HW + g] * sc;
            v.z = imb[(size_t)5 * HW + g] * sc;
            v.w = 0.f;
        } else {
            m.x = 1e9f; m.y = 1e9f;
            v.x = v.y = v.z = v.w = 0.f;
        }
        smot[ly][lx] = m;
        sim[ly][lx]  = v;
    }
    __syncthreads();

    int lx = tid & 31, ly = tid >> 5;
    int y = by0 + ly, x = bx0 + lx;

    float a0 = 0.f, a1 = 0.f, a2 = 0.f;
    #pragma unroll
    for (int dy = -5; dy <= 5; ++dy) {
        #pragma unroll
        for (int dx = -5; dx <= 5; ++dx) {
            float2 m = smot[ly + HALO + dy][lx + HALO + dx];
            float wb = 1.f - fabsf(m.y - (float)dy);
            float wa = 1.f - fabsf(m.x - (float)dx);
            if (wb > 0.f && wa > 0.f) {
                float w = wb * wa;
                float4 v = sim[ly + HALO + dy][lx + HALO + dx];
                a0 += w * v.x;
                a1 += w * v.y;
                a2 += w * v.z;
            }
        }
    }

    float* predb = out + OFF_PRED + (size_t)b * 3 * HW + y * 128 + x;
    predb[0]               = a0;
    predb[(size_t)HW]      = a1;
    predb[(size_t)2 * HW]  = a2;
}

extern "C" void kernel_launch(void* const* d_in, const int* in_sizes, int n_in,
                              void* d_out, int out_size, void* d_ws, size_t ws_size,
                              hipStream_t stream) {
    const float* im_input = (const float*)d_in[0];   // (8, 6, 128, 128)
    const float* motion   = (const float*)d_in[1];   // (8, 2, 128, 128)
    // d_in[2] = m_kernel: identity by construction, unused.
    float* out = (float*)d_out;

    dim3 block(256);
    dim3 grid(8 * 64);   // 8 batches x (4 x 16) tiles
    k_mask_seg<<<grid, block, 0, stream>>>(motion, out);
    k_pred<<<grid, block, 0, stream>>>(motion, im_input, out);
}

// Round 3
// 32.624 us; speedup vs baseline: 2.4339x; 1.0939x over previous
//
#include <hip/hip_runtime.h>

#define HW       16384                  // 128*128
#define NCLASS   121

// d_out layout (flat f32, return order: pred, m_mask, disappear, appear)
#define OFF_PRED 0
#define OFF_MASK (8 * 3 * HW)                    // 393216
#define OFF_DIS  (OFF_MASK + 8 * NCLASS * HW)    // 16252928
#define OFF_APP  (OFF_DIS + 8 * HW)              // 16384000

__device__ __forceinline__ float hatf(float u) { return fmaxf(0.f, 1.f - fabsf(u)); }

// K1: grid = 8 batches * 16 row-tiles * 12 chunks. Tile = 128 wide x 8 rows.
// chunk < 11 : write m_mask channel row kb=chunk (11 channels) as float4 stores.
// chunk == 11: seg scatter into LDS (ds_add_f32) -> disappear/appear writes.
__global__ __launch_bounds__(256) void k_mask_seg(const float* __restrict__ motion,
                                                  float* __restrict__ out) {
    __shared__ float sseg[8][128];      // 4 KB, used by chunk 11 only
    int blk   = blockIdx.x;
    int chunk = blk % 12;
    int tl    = blk / 12;               // 0..127
    int b     = tl >> 4;
    int y0    = (tl & 15) << 3;
    int tid   = threadIdx.x;

    const float* motx = motion + (size_t)(b * 2) * HW;
    const float* moty = motx + HW;

    if (chunk < 11) {
        // ---- m_mask row kb = chunk, 4 consecutive x-pixels per thread ----
        int kb = chunk;
        int ly = tid >> 5;              // 0..7
        int x4 = (tid & 31) << 2;       // 0,4,...,124
        int g  = (y0 + ly) * 128 + x4;
        float4 mx = *(const float4*)(motx + g);
        float4 my = *(const float4*)(moty + g);
        float kbo = (float)(kb - 5);
        float4 bv;
        bv.x = hatf(my.x - kbo); bv.y = hatf(my.y - kbo);
        bv.z = hatf(my.z - kbo); bv.w = hatf(my.w - kbo);
        float* mm = out + OFF_MASK + ((size_t)(b * NCLASS + kb * 11)) * HW + g;
        #pragma unroll
        for (int ka = 0; ka < 11; ++ka) {
            float kao = (float)(ka - 5);
            float4 v;
            v.x = bv.x * hatf(mx.x - kao);
            v.y = bv.y * hatf(mx.y - kao);
            v.z = bv.z * hatf(mx.z - kao);
            v.w = bv.w * hatf(mx.w - kao);
            *(float4*)(mm + (size_t)ka * HW) = v;
        }
    } else {
        // ---- seg scatter: sources = 18 full rows [y0-5, y0+13) ----
        ((float4*)&sseg[0][0])[tid] = make_float4(0.f, 0.f, 0.f, 0.f);
        __syncthreads();
        #pragma unroll
        for (int it = 0; it < 9; ++it) {
            int idx = tid + it * 256;            // 0..2303
            int sy  = y0 - 5 + (idx >> 7);
            int sx  = idx & 127;
            if (sy >= 0 && sy < 128) {
                int s = sy * 128 + sx;
                float mx = motx[s], my = moty[s];
                float flx = floorf(mx), fly = floorf(my);
                float fa = mx - flx, fb = my - fly;
                int ia = (int)flx + 5, ib = (int)fly + 5;
                float wa0 = 1.f - fa, wa1 = fa;
                float wb0 = 1.f - fb, wb1 = fb;
                #pragma unroll
                for (int j = 0; j < 2; ++j) {
                    int ty = sy - (ib + j) + 5;
                    if (ty < y0 || ty >= y0 + 8) continue;
                    float wb = j ? wb1 : wb0;
                    #pragma unroll
                    for (int i = 0; i < 2; ++i) {
                        int tx = sx - (ia + i) + 5;
                        if (tx < 0 || tx >= 128) continue;
                        atomicAdd(&sseg[ty - y0][tx], wb * (i ? wa1 : wa0));
                    }
                }
            }
        }
        __syncthreads();
        int ly = tid >> 5;
        int x4 = (tid & 31) << 2;
        float4 s4 = *(float4*)&sseg[ly][x4];
        float4 d4, a4;
        d4.x = fmaxf(s4.x - 1.f, 0.f); a4.x = fmaxf(1.f - s4.x, 0.f);
        d4.y = fmaxf(s4.y - 1.f, 0.f); a4.y = fmaxf(1.f - s4.y, 0.f);
        d4.z = fmaxf(s4.z - 1.f, 0.f); a4.z = fmaxf(1.f - s4.z, 0.f);
        d4.w = fmaxf(s4.w - 1.f, 0.f); a4.w = fmaxf(1.f - s4.w, 0.f);
        int p = b * HW + (y0 + ly) * 128 + x4;
        *(float4*)(out + OFF_DIS + p) = d4;
        *(float4*)(out + OFF_APP + p) = a4;
    }
}

// K2: pred via LDS scatter. grid = 8 batches * 32 row-tiles, tile = 128 x 4.
// Each source pixel scatters w * im_scaled (3 ch) to <=4 targets in LDS.
__global__ __launch_bounds__(256) void k_pred(const float* __restrict__ motion,
                                              const float* __restrict__ im_input,
                                              float* __restrict__ out) {
    __shared__ float spred[3][4][128];  // 6 KB
    int blk = blockIdx.x;
    int b   = blk >> 5;
    int y0  = (blk & 31) << 2;
    int tid = threadIdx.x;

    const float* motx = motion + (size_t)(b * 2) * HW;
    const float* moty = motx + HW;
    const float* imb  = im_input + (size_t)b * 6 * HW;
    const float* disb = out + OFF_DIS + (size_t)b * HW;

    for (int i = tid; i < 384; i += 256)
        ((float4*)&spred[0][0][0])[i] = make_float4(0.f, 0.f, 0.f, 0.f);
    __syncthreads();

    #pragma unroll
    for (int it = 0; it < 7; ++it) {
        int idx = tid + it * 256;               // 0..1791, 14 rows
        int sy  = y0 - 5 + (idx >> 7);
        int sx  = idx & 127;
        if (sy >= 0 && sy < 128) {
            int s = sy * 128 + sx;
            float mx = motx[s], my = moty[s];
            float sc = 1.f - disb[s];
            float i0 = imb[(size_t)3 * HW + s] * sc;
            float i1 = imb[(size_t)4 * HW + s] * sc;
            float i2 = imb[(size_t)5 * HW + s] * sc;
            float flx = floorf(mx), fly = floorf(my);
            float fa = mx - flx, fb = my - fly;
            int ia = (int)flx + 5, ib = (int)fly + 5;
            float wa0 = 1.f - fa, wa1 = fa;
            float wb0 = 1.f - fb, wb1 = fb;
            #pragma unroll
            for (int j = 0; j < 2; ++j) {
                int ty = sy - (ib + j) + 5;
                if (ty < y0 || ty >= y0 + 4) continue;
                float wb = j ? wb1 : wb0;
                #pragma unroll
                for (int i = 0; i < 2; ++i) {
                    int tx = sx - (ia + i) + 5;
                    if (tx < 0 || tx >= 128) continue;
                    float w = wb * (i ? wa1 : wa0);
                    int tr = ty - y0;
                    atomicAdd(&spred[0][tr][tx], w * i0);
                    atomicAdd(&spred[1][tr][tx], w * i1);
                    atomicAdd(&spred[2][tr][tx], w * i2);
                }
            }
        }
    }
    __syncthreads();

    // write central 4 rows x 128, 2 px/thread, 3 channels
    int p  = tid * 2;
    int ly = p >> 7;
    int x  = p & 127;
    float* predb = out + OFF_PRED + (size_t)b * 3 * HW + (y0 + ly) * 128 + x;
    #pragma unroll
    for (int ch = 0; ch < 3; ++ch) {
        float2 v;
        v.x = spred[ch][ly][x];
        v.y = spred[ch][ly][x + 1];
        *(float2*)(predb + (size_t)ch * HW) = v;
    }
}

extern "C" void kernel_launch(void* const* d_in, const int* in_sizes, int n_in,
                              void* d_out, int out_size, void* d_ws, size_t ws_size,
                              hipStream_t stream) {
    const float* im_input = (const float*)d_in[0];   // (8, 6, 128, 128)
    const float* motion   = (const float*)d_in[1];   // (8, 2, 128, 128)
    // d_in[2] = m_kernel: identity by construction, unused.
    float* out = (float*)d_out;

    k_mask_seg<<<dim3(8 * 16 * 12), dim3(256), 0, stream>>>(motion, out);
    k_pred<<<dim3(8 * 32), dim3(256), 0, stream>>>(motion, im_input, out);
}